// Round 12
// baseline (791.328 us; speedup 1.0000x reference)
//
#include <hip/hip_runtime.h>
#include <hip/hip_bf16.h>

#define NN 16384
#define DD 128
#define BK 64          // k floats per phase (2 k-tiles of 32)
#define NT (NN / BK)   // 256 phases

typedef __attribute__((ext_vector_type(8))) short short8;
typedef __attribute__((ext_vector_type(4))) float f32x4;

__device__ __forceinline__ short f2bf(float f) {
  union { float f; unsigned u; } v; v.f = f;
  unsigned r = v.u + 0x7fffu + ((v.u >> 16) & 1u);   // RNE f32->bf16
  return (short)(r >> 16);
}
__device__ __forceinline__ float bf2f(short s) {
  union { unsigned u; float f; } v; v.u = ((unsigned)(unsigned short)s) << 16;
  return v.f;
}

#define WAITV(n) asm volatile("s_waitcnt vmcnt(" #n ")" ::: "memory")

// ---------------------------------------------------------------------------
// small GEMM: T = In @ W, written in MFMA B-fragment-major layout:
//   element (d, k):  kt=k>>5, dt=d>>4, lane=(d&15)|(((k>>3)&3)<<4), e=k&7
//   Tf[(((kt*8)+dt)*64 + lane)*8 + e]
// ---------------------------------------------------------------------------
template<int IN_BF16>
__global__ __launch_bounds__(256, 1)
void small_gemm(const void* __restrict__ In_, const float* __restrict__ W,
                short* __restrict__ Tf)
{
  __shared__ float sW[DD * DD];   // 64 KB
  const int tid = threadIdx.x;
  {
    const float4* W4 = (const float4*)W;
    float4* sW4 = (float4*)sW;
#pragma unroll
    for (int i = 0; i < 16; ++i) sW4[tid + 256 * i] = W4[tid + 256 * i];
  }
  __syncthreads();

  const int k0 = blockIdx.x * 16;
  const int kk = tid & 15;        // k-row within tile
  const int q  = tid >> 4;        // d-chunk 0..15 -> d = 8q..8q+7
  const long rowoff = (long)(k0 + kk) * DD;

  float acc[8] = {0.f, 0.f, 0.f, 0.f, 0.f, 0.f, 0.f, 0.f};
  if (IN_BF16) {
    const short8* In8 = (const short8*)((const short*)In_ + rowoff);
    for (int j8 = 0; j8 < 16; ++j8) {
      short8 a8 = In8[j8];
#pragma unroll
      for (int c = 0; c < 8; ++c) {
        float a = bf2f(a8[c]);
#pragma unroll
        for (int dd = 0; dd < 8; ++dd)
          acc[dd] += a * sW[(j8 * 8 + c) * DD + q * 8 + dd];
      }
    }
  } else {
    const float4* In4 = (const float4*)((const float*)In_ + rowoff);
    for (int j4 = 0; j4 < 32; ++j4) {
      float4 a4 = In4[j4];
      float av[4] = {a4.x, a4.y, a4.z, a4.w};
#pragma unroll
      for (int c = 0; c < 4; ++c)
#pragma unroll
        for (int dd = 0; dd < 8; ++dd)
          acc[dd] += av[c] * sW[(j4 * 4 + c) * DD + q * 8 + dd];
    }
  }

  const int k    = k0 + kk;
  const int kt   = k >> 5;
  const int ksub = (k >> 3) & 3;
  const int e    = k & 7;
#pragma unroll
  for (int dd = 0; dd < 8; ++dd) {
    const int d  = q * 8 + dd;
    const int dt = d >> 4;
    const int lf = (d & 15) | (ksub << 4);
    Tf[((((long)kt * 8) + dt) * 64 + lf) * 8 + e] = f2bf(acc[dd]);
  }
}

// ---------------------------------------------------------------------------
// BARRIER-FREE aggregation: Out = relu(A @ T), T fragment-major bf16.
// Block = 64 rows, 4 waves; each wave owns a PRIVATE 16-row strip:
//   - A: wave-private gll->LDS (4 KB/phase, lane-contiguous 1 KB/instr,
//        sc1|nt to bypass L2), 4-buf rotation, counted per-wave vmcnt.
//   - B: read DIRECTLY from global Tf (L2-resident 4 MB; 1 KB/instr,
//        L1 catches 4-wave reuse). No LDS for B.
// => ZERO s_barrier: no inter-wave lockstep, each wave free-runs.
// vmcnt bounds (in-order retire; N = #VMEM issued after A(t)'s gll):
//   peel 8/24, steady 40 (=B16+A4+B16+A4), drain 40/36/32.
// ---------------------------------------------------------------------------
template<int WRITE_BF16>
__global__ __launch_bounds__(256, 1)
void agg_nb(const float* __restrict__ A, const short* __restrict__ Bf,
            void* __restrict__ out_)
{
  __shared__ __align__(16) char sA[65536];   // [wave][buf][4096]

  const int tid  = threadIdx.x;
  const int lane = tid & 63;
  const int w    = tid >> 6;                 // wave 0..3
  const long rb  = (long)blockIdx.x * 64 + w * 16;   // wave's row base
  const int arow = lane & 15;
  const int kgrp = lane >> 4;

  // wave-private staging geometry: 16 rows x 256 B, XOR-swizzle (row&7)<<4
  int rowi[4], colfi[4];
#pragma unroll
  for (int i = 0; i < 4; ++i) {
    const int o  = i * 1024 + lane * 16;
    const int rr = o >> 8;                   // 0..15
    const int cb = (o & 255) ^ ((rr & 7) << 4);
    rowi[i] = rr;
    colfi[i] = cb >> 2;
  }
  char* ldsw = sA + w * 16384;

  f32x4 acc[8];
#pragma unroll
  for (int dt = 0; dt < 8; ++dt) acc[dt] = (f32x4){0.f, 0.f, 0.f, 0.f};

  auto STAGE = [&](int buf, int t) {
#pragma unroll
    for (int i = 0; i < 4; ++i) {
      const float* g = A + (rb + rowi[i]) * (long)NN + t * BK + colfi[i];
      __builtin_amdgcn_global_load_lds(
          (const __attribute__((address_space(1))) unsigned int*)g,
          (__attribute__((address_space(3))) unsigned int*)(ldsw + buf * 4096 + i * 1024),
          16, 0, 0x12);
    }
  };

  auto COMPUTE = [&](int buf, int t) {
    const char* la = ldsw + buf * 4096;
    const int sw = (arow & 7) << 4;
#pragma unroll
    for (int ks = 0; ks < 2; ++ks) {
      f32x4 a0 = *(const f32x4*)(la + arow * 256 + ((ks * 128 + kgrp * 32) ^ sw));
      f32x4 a1 = *(const f32x4*)(la + arow * 256 + ((ks * 128 + kgrp * 32 + 16) ^ sw));
      short8 af;
      af[0] = f2bf(a0.x); af[1] = f2bf(a0.y); af[2] = f2bf(a0.z); af[3] = f2bf(a0.w);
      af[4] = f2bf(a1.x); af[5] = f2bf(a1.y); af[6] = f2bf(a1.z); af[7] = f2bf(a1.w);
      const long kt = 2 * t + ks;
#pragma unroll
      for (int dt = 0; dt < 8; ++dt) {
        short8 bf = *(const short8*)(Bf + ((kt * 8 + dt) * 64 + lane) * 8);
        acc[dt] = __builtin_amdgcn_mfma_f32_16x16x32_bf16(af, bf, acc[dt], 0, 0, 0);
      }
    }
  };

  // prologue: 3 private tiles in flight (12 gll)
  STAGE(0, 0); STAGE(1, 1); STAGE(2, 2);

  WAITV(8);  COMPUTE(0, 0); STAGE(3, 3);
  WAITV(24); COMPUTE(1, 1); STAGE(0, 4);
  for (int t = 2; t < NT - 3; ++t) {
    WAITV(40); COMPUTE(t & 3, t); STAGE((t + 3) & 3, t + 3);
  }
  WAITV(40); COMPUTE((NT - 3) & 3, NT - 3);
  WAITV(36); COMPUTE((NT - 2) & 3, NT - 2);
  WAITV(32); COMPUTE((NT - 1) & 3, NT - 1);

  // epilogue: relu + store (C layout: row = kgrp*4 + r, col = dt*16 + arow)
#pragma unroll
  for (int dt = 0; dt < 8; ++dt) {
#pragma unroll
    for (int r = 0; r < 4; ++r) {
      float v = acc[dt][r];
      v = v > 0.f ? v : 0.f;
      const long row = rb + kgrp * 4 + r;
      const int  col = dt * 16 + arow;
      if (WRITE_BF16)
        __builtin_nontemporal_store(f2bf(v), (short*)out_ + row * DD + col);
      else
        __builtin_nontemporal_store(v, (float*)out_ + row * DD + col);
    }
  }
}

// ---------------------------------------------------------------------------
extern "C" void kernel_launch(void* const* d_in, const int* in_sizes, int n_in,
                              void* d_out, int out_size, void* d_ws, size_t ws_size,
                              hipStream_t stream)
{
  const float* A  = (const float*)d_in[0];   // [16384][16384]
  const float* X  = (const float*)d_in[1];   // [16384][128]
  const float* W0 = (const float*)d_in[2];   // [128][128]
  const float* W1 = (const float*)d_in[3];   // [128][128]

  short* Tf = (short*)d_ws;                  // bf16 fragment-major T (4 MB)
  short* H1 = Tf + (size_t)DD * NN;          // bf16 [16384][128] post-relu H1

  // layer 0: T0 = X @ W0 ; H1 = relu(A @ T0)
  small_gemm<0><<<NN / 16, 256, 0, stream>>>(X, W0, Tf);
  agg_nb<1><<<NN / 64, 256, 0, stream>>>(A, Tf, H1);
  // layer 1: T1 = H1 @ W1 ; out = relu(A @ T1)
  small_gemm<1><<<NN / 16, 256, 0, stream>>>(H1, W1, Tf);
  agg_nb<0><<<NN / 64, 256, 0, stream>>>(A, Tf, d_out);
}

// Round 13
// 451.880 us; speedup vs baseline: 1.7512x; 1.7512x over previous
//
#include <hip/hip_runtime.h>
#include <hip/hip_bf16.h>

#define NN 16384
#define DD 128
#define BK 64          // k floats per pipeline stage
#define NT (NN / BK)   // 256 stages

typedef __attribute__((ext_vector_type(8))) short short8;
typedef __attribute__((ext_vector_type(4))) float f32x4;

__device__ __forceinline__ short f2bf(float f) {
  union { float f; unsigned u; } v; v.f = f;
  unsigned r = v.u + 0x7fffu + ((v.u >> 16) & 1u);   // RNE f32->bf16
  return (short)(r >> 16);
}
__device__ __forceinline__ float bf2f(short s) {
  union { unsigned u; float f; } v; v.u = ((unsigned)(unsigned short)s) << 16;
  return v.f;
}

#define WAITV(n) asm volatile("s_waitcnt vmcnt(" #n ")" ::: "memory")
#define BAR()    do { __builtin_amdgcn_s_barrier(); asm volatile("" ::: "memory"); } while (0)

// ---------------------------------------------------------------------------
// small GEMM: T = In @ W, written in MFMA B-fragment-major layout:
//   element (d, k):  kt=k>>5, dt=d>>4, lane=(d&15)|(((k>>3)&3)<<4), e=k&7
//   Tf[(((kt*8)+dt)*64 + lane)*8 + e]
// ---------------------------------------------------------------------------
template<int IN_BF16>
__global__ __launch_bounds__(256, 1)
void small_gemm(const void* __restrict__ In_, const float* __restrict__ W,
                short* __restrict__ Tf)
{
  __shared__ float sW[DD * DD];   // 64 KB
  const int tid = threadIdx.x;
  {
    const float4* W4 = (const float4*)W;
    float4* sW4 = (float4*)sW;
#pragma unroll
    for (int i = 0; i < 16; ++i) sW4[tid + 256 * i] = W4[tid + 256 * i];
  }
  __syncthreads();

  const int k0 = blockIdx.x * 16;
  const int kk = tid & 15;        // k-row within tile
  const int q  = tid >> 4;        // d-chunk 0..15 -> d = 8q..8q+7
  const long rowoff = (long)(k0 + kk) * DD;

  float acc[8] = {0.f, 0.f, 0.f, 0.f, 0.f, 0.f, 0.f, 0.f};
  if (IN_BF16) {
    const short8* In8 = (const short8*)((const short*)In_ + rowoff);
    for (int j8 = 0; j8 < 16; ++j8) {
      short8 a8 = In8[j8];
#pragma unroll
      for (int c = 0; c < 8; ++c) {
        float a = bf2f(a8[c]);
#pragma unroll
        for (int dd = 0; dd < 8; ++dd)
          acc[dd] += a * sW[(j8 * 8 + c) * DD + q * 8 + dd];
      }
    }
  } else {
    const float4* In4 = (const float4*)((const float*)In_ + rowoff);
    for (int j4 = 0; j4 < 32; ++j4) {
      float4 a4 = In4[j4];
      float av[4] = {a4.x, a4.y, a4.z, a4.w};
#pragma unroll
      for (int c = 0; c < 4; ++c)
#pragma unroll
        for (int dd = 0; dd < 8; ++dd)
          acc[dd] += av[c] * sW[(j4 * 4 + c) * DD + q * 8 + dd];
    }
  }

  const int k    = k0 + kk;
  const int kt   = k >> 5;
  const int ksub = (k >> 3) & 3;
  const int e    = k & 7;
#pragma unroll
  for (int dd = 0; dd < 8; ++dd) {
    const int d  = q * 8 + dd;
    const int dt = d >> 4;
    const int lf = (d & 15) | (ksub << 4);
    Tf[((((long)kt * 8) + dt) * 64 + lf) * 8 + e] = f2bf(acc[dd]);
  }
}

// ---------------------------------------------------------------------------
// aggregation: Out = relu(A @ T), T fragment-major bf16.  (R9 structure)
// Block = 64 rows (4 waves x 16 rows), grid 256 = 1 block/CU.
// BOTH operands staged via global_load_lds (lane-contiguous 1 KB per instr).
// A staged fp32, XOR-swizzle (row&7)<<4 (pre-swizzled source + swizzled
// ds_read). A aux = 0x2 (NT ONLY — no-allocate/evict-first keeps Tf
// L2-resident, but keeps normal L2 line-granularity merging; R13 change:
// was 0x12 sc1|nt whose full L2 bypass may issue sub-line DRAM requests).
// B aux=0 (L2-resident). 4-buffer pipeline, distance 3, counted vmcnt.
// ---------------------------------------------------------------------------
template<int WRITE_BF16>
__global__ __launch_bounds__(256, 1)
void agg_kernel(const float* __restrict__ A, const short* __restrict__ Bf,
                void* __restrict__ out_)
{
  __shared__ __align__(16) char sMem[131072];    // A: 4x16KB | B: 4x16KB
  char* sA = sMem;
  char* sB = sMem + 65536;

  const int tid  = threadIdx.x;
  const int lane = tid & 63;
  const int w    = tid >> 6;                     // wave 0..3
  const long rb  = (long)blockIdx.x * 64;        // block row base
  const int arow = lane & 15;
  const int kgrp = lane >> 4;

  int rowi[4], colfi[4];
#pragma unroll
  for (int i = 0; i < 4; ++i) {
    const int o  = w * 4096 + i * 1024 + lane * 16;
    const int rr = o >> 8;
    const int cb = (o & 255) ^ ((rr & 7) << 4);
    rowi[i] = rr;
    colfi[i] = cb >> 2;
  }
  const short* gsrcB = Bf + w * 2048 + lane * 8;
  char* ldsAu = sA + w * 4096;
  char* ldsBu = sB + w * 4096;

  f32x4 acc[8];
#pragma unroll
  for (int dt = 0; dt < 8; ++dt) acc[dt] = (f32x4){0.f, 0.f, 0.f, 0.f};

  auto STAGE = [&](int buf, int t) {
#pragma unroll
    for (int i = 0; i < 4; ++i) {
      const float* g = A + (rb + rowi[i]) * (long)NN + t * BK + colfi[i];
      __builtin_amdgcn_global_load_lds(
          (const __attribute__((address_space(1))) unsigned int*)g,
          (__attribute__((address_space(3))) unsigned int*)(ldsAu + buf * 16384 + i * 1024),
          16, 0, 0x2);
    }
    const short* g = gsrcB + (long)t * 8192;
#pragma unroll
    for (int i = 0; i < 4; ++i)
      __builtin_amdgcn_global_load_lds(
          (const __attribute__((address_space(1))) unsigned int*)(g + i * 512),
          (__attribute__((address_space(3))) unsigned int*)(ldsBu + buf * 16384 + i * 1024),
          16, 0, 0);
  };

  auto COMPUTE = [&](int buf) {
    const char* la = sA + buf * 16384;
    const char* lb = sB + buf * 16384 + lane * 16;
    const int row = w * 16 + arow;
    const int sw  = (arow & 7) << 4;
#pragma unroll
    for (int ks = 0; ks < 2; ++ks) {
      f32x4 a0 = *(const f32x4*)(la + row * 256 + ((ks * 128 + kgrp * 32) ^ sw));
      f32x4 a1 = *(const f32x4*)(la + row * 256 + ((ks * 128 + kgrp * 32 + 16) ^ sw));
      short8 af;
      af[0] = f2bf(a0.x); af[1] = f2bf(a0.y); af[2] = f2bf(a0.z); af[3] = f2bf(a0.w);
      af[4] = f2bf(a1.x); af[5] = f2bf(a1.y); af[6] = f2bf(a1.z); af[7] = f2bf(a1.w);
#pragma unroll
      for (int dt = 0; dt < 8; ++dt) {
        short8 bf = *(const short8*)(lb + (ks * 8 + dt) * 1024);
        acc[dt] = __builtin_amdgcn_mfma_f32_16x16x32_bf16(af, bf, acc[dt], 0, 0, 0);
      }
    }
  };

  // prologue: stage tiles 0,1,2 (24 VMEM outstanding per wave)
  STAGE(0, 0); STAGE(1, 1); STAGE(2, 2);

  int t = 0;
  for (; t < NT - 4; t += 4) {
    WAITV(16); BAR(); STAGE(3, t + 3); COMPUTE(0);
    WAITV(16); BAR(); STAGE(0, t + 4); COMPUTE(1);
    WAITV(16); BAR(); STAGE(1, t + 5); COMPUTE(2);
    WAITV(16); BAR(); STAGE(2, t + 6); COMPUTE(3);
  }
  // t == NT-4: stage last tile NT-1, then drain
  WAITV(16); BAR(); STAGE(3, t + 3); COMPUTE(0);
  WAITV(16); BAR(); COMPUTE(1);
  WAITV(8);  BAR(); COMPUTE(2);
  WAITV(0);  BAR(); COMPUTE(3);

  // epilogue: relu + store (C layout: row = kgrp*4 + r, col = dt*16 + arow)
#pragma unroll
  for (int dt = 0; dt < 8; ++dt) {
#pragma unroll
    for (int r = 0; r < 4; ++r) {
      float v = acc[dt][r];
      v = v > 0.f ? v : 0.f;
      const long row = rb + w * 16 + kgrp * 4 + r;
      const int  col = dt * 16 + arow;
      if (WRITE_BF16)
        __builtin_nontemporal_store(f2bf(v), (short*)out_ + row * DD + col);
      else
        __builtin_nontemporal_store(v, (float*)out_ + row * DD + col);
    }
  }
}

// ---------------------------------------------------------------------------
extern "C" void kernel_launch(void* const* d_in, const int* in_sizes, int n_in,
                              void* d_out, int out_size, void* d_ws, size_t ws_size,
                              hipStream_t stream)
{
  const float* A  = (const float*)d_in[0];   // [16384][16384]
  const float* X  = (const float*)d_in[1];   // [16384][128]
  const float* W0 = (const float*)d_in[2];   // [128][128]
  const float* W1 = (const float*)d_in[3];   // [128][128]

  short* Tf = (short*)d_ws;                  // bf16 fragment-major T (4 MB)
  short* H1 = Tf + (size_t)DD * NN;          // bf16 [16384][128] post-relu H1

  // layer 0: T0 = X @ W0 ; H1 = relu(A @ T0)
  small_gemm<0><<<NN / 16, 256, 0, stream>>>(X, W0, Tf);
  agg_kernel<1><<<NN / 64, 256, 0, stream>>>(A, Tf, H1);
  // layer 1: T1 = H1 @ W1 ; out = relu(A @ T1)
  small_gemm<1><<<NN / 16, 256, 0, stream>>>(H1, W1, Tf);
  agg_kernel<0><<<NN / 64, 256, 0, stream>>>(A, Tf, d_out);
}

// Round 14
// 437.071 us; speedup vs baseline: 1.8105x; 1.0339x over previous
//
#include <hip/hip_runtime.h>
#include <hip/hip_bf16.h>

#define NN 16384
#define DD 128
#define BK 64          // k floats per pipeline stage
#define NT (NN / BK)   // 256 stages

typedef __attribute__((ext_vector_type(8))) short short8;
typedef __attribute__((ext_vector_type(4))) float f32x4;

__device__ __forceinline__ short f2bf(float f) {
  union { float f; unsigned u; } v; v.f = f;
  unsigned r = v.u + 0x7fffu + ((v.u >> 16) & 1u);   // RNE f32->bf16
  return (short)(r >> 16);
}
__device__ __forceinline__ float bf2f(short s) {
  union { unsigned u; float f; } v; v.u = ((unsigned)(unsigned short)s) << 16;
  return v.f;
}

#define WAITV(n) asm volatile("s_waitcnt vmcnt(" #n ")" ::: "memory")
#define BAR()    do { __builtin_amdgcn_s_barrier(); asm volatile("" ::: "memory"); } while (0)

// ---------------------------------------------------------------------------
// small GEMM: T = In @ W, written in MFMA B-fragment-major layout:
//   element (d, k):  kt=k>>5, dt=d>>4, lane=(d&15)|(((k>>3)&3)<<4), e=k&7
//   Tf[(((kt*8)+dt)*64 + lane)*8 + e]
// ---------------------------------------------------------------------------
template<int IN_BF16>
__global__ __launch_bounds__(256, 1)
void small_gemm(const void* __restrict__ In_, const float* __restrict__ W,
                short* __restrict__ Tf)
{
  __shared__ float sW[DD * DD];   // 64 KB
  const int tid = threadIdx.x;
  {
    const float4* W4 = (const float4*)W;
    float4* sW4 = (float4*)sW;
#pragma unroll
    for (int i = 0; i < 16; ++i) sW4[tid + 256 * i] = W4[tid + 256 * i];
  }
  __syncthreads();

  const int k0 = blockIdx.x * 16;
  const int kk = tid & 15;        // k-row within tile
  const int q  = tid >> 4;        // d-chunk 0..15 -> d = 8q..8q+7
  const long rowoff = (long)(k0 + kk) * DD;

  float acc[8] = {0.f, 0.f, 0.f, 0.f, 0.f, 0.f, 0.f, 0.f};
  if (IN_BF16) {
    const short8* In8 = (const short8*)((const short*)In_ + rowoff);
    for (int j8 = 0; j8 < 16; ++j8) {
      short8 a8 = In8[j8];
#pragma unroll
      for (int c = 0; c < 8; ++c) {
        float a = bf2f(a8[c]);
#pragma unroll
        for (int dd = 0; dd < 8; ++dd)
          acc[dd] += a * sW[(j8 * 8 + c) * DD + q * 8 + dd];
      }
    }
  } else {
    const float4* In4 = (const float4*)((const float*)In_ + rowoff);
    for (int j4 = 0; j4 < 32; ++j4) {
      float4 a4 = In4[j4];
      float av[4] = {a4.x, a4.y, a4.z, a4.w};
#pragma unroll
      for (int c = 0; c < 4; ++c)
#pragma unroll
        for (int dd = 0; dd < 8; ++dd)
          acc[dd] += av[c] * sW[(j4 * 4 + c) * DD + q * 8 + dd];
    }
  }

  const int k    = k0 + kk;
  const int kt   = k >> 5;
  const int ksub = (k >> 3) & 3;
  const int e    = k & 7;
#pragma unroll
  for (int dd = 0; dd < 8; ++dd) {
    const int d  = q * 8 + dd;
    const int dt = d >> 4;
    const int lf = (d & 15) | (ksub << 4);
    Tf[((((long)kt * 8) + dt) * 64 + lf) * 8 + e] = f2bf(acc[dd]);
  }
}

// ---------------------------------------------------------------------------
// FUSED agg layer 1: T1f = frag((relu(A @ T0)) @ W1)  — no H1 round-trip,
// no separate small_gemm<1> launch. Main loop = R9 exactly (best measured).
// Epilogue per wave: relu+transpose acc -> LDS A-frag layout; W1 staged to
// LDS as bf16 B-frags by all 256 threads; 32 MFMAs; pair-wise LDS assembly
// into B-frag-linear; 1 KB contiguous global stores of T1f.
// ---------------------------------------------------------------------------
__global__ __launch_bounds__(256, 1)
void agg_fused(const float* __restrict__ A, const short* __restrict__ Bf,
               const float* __restrict__ W1, short* __restrict__ T1f)
{
  __shared__ __align__(16) char sMem[131072];    // A: 4x16KB | B: 4x16KB
  char* sA = sMem;
  char* sB = sMem + 65536;

  const int tid  = threadIdx.x;
  const int lane = tid & 63;
  const int w    = tid >> 6;                     // wave 0..3
  const long rb  = (long)blockIdx.x * 64;        // block row base
  const int arow = lane & 15;
  const int kgrp = lane >> 4;

  int rowi[4], colfi[4];
#pragma unroll
  for (int i = 0; i < 4; ++i) {
    const int o  = w * 4096 + i * 1024 + lane * 16;
    const int rr = o >> 8;
    const int cb = (o & 255) ^ ((rr & 7) << 4);
    rowi[i] = rr;
    colfi[i] = cb >> 2;
  }
  const short* gsrcB = Bf + w * 2048 + lane * 8;
  char* ldsAu = sA + w * 4096;
  char* ldsBu = sB + w * 4096;

  f32x4 acc[8];
#pragma unroll
  for (int dt = 0; dt < 8; ++dt) acc[dt] = (f32x4){0.f, 0.f, 0.f, 0.f};

  auto STAGE = [&](int buf, int t) {
#pragma unroll
    for (int i = 0; i < 4; ++i) {
      const float* g = A + (rb + rowi[i]) * (long)NN + t * BK + colfi[i];
      __builtin_amdgcn_global_load_lds(
          (const __attribute__((address_space(1))) unsigned int*)g,
          (__attribute__((address_space(3))) unsigned int*)(ldsAu + buf * 16384 + i * 1024),
          16, 0, 0x12);
    }
    const short* g = gsrcB + (long)t * 8192;
#pragma unroll
    for (int i = 0; i < 4; ++i)
      __builtin_amdgcn_global_load_lds(
          (const __attribute__((address_space(1))) unsigned int*)(g + i * 512),
          (__attribute__((address_space(3))) unsigned int*)(ldsBu + buf * 16384 + i * 1024),
          16, 0, 0);
  };

  auto COMPUTE = [&](int buf) {
    const char* la = sA + buf * 16384;
    const char* lb = sB + buf * 16384 + lane * 16;
    const int row = w * 16 + arow;
    const int sw  = (arow & 7) << 4;
#pragma unroll
    for (int ks = 0; ks < 2; ++ks) {
      f32x4 a0 = *(const f32x4*)(la + row * 256 + ((ks * 128 + kgrp * 32) ^ sw));
      f32x4 a1 = *(const f32x4*)(la + row * 256 + ((ks * 128 + kgrp * 32 + 16) ^ sw));
      short8 af;
      af[0] = f2bf(a0.x); af[1] = f2bf(a0.y); af[2] = f2bf(a0.z); af[3] = f2bf(a0.w);
      af[4] = f2bf(a1.x); af[5] = f2bf(a1.y); af[6] = f2bf(a1.z); af[7] = f2bf(a1.w);
#pragma unroll
      for (int dt = 0; dt < 8; ++dt) {
        short8 bf = *(const short8*)(lb + (ks * 8 + dt) * 1024);
        acc[dt] = __builtin_amdgcn_mfma_f32_16x16x32_bf16(af, bf, acc[dt], 0, 0, 0);
      }
    }
  };

  STAGE(0, 0); STAGE(1, 1); STAGE(2, 2);

  int t = 0;
  for (; t < NT - 4; t += 4) {
    WAITV(16); BAR(); STAGE(3, t + 3); COMPUTE(0);
    WAITV(16); BAR(); STAGE(0, t + 4); COMPUTE(1);
    WAITV(16); BAR(); STAGE(1, t + 5); COMPUTE(2);
    WAITV(16); BAR(); STAGE(2, t + 6); COMPUTE(3);
  }
  WAITV(16); BAR(); STAGE(3, t + 3); COMPUTE(0);
  WAITV(16); BAR(); COMPUTE(1);
  WAITV(8);  BAR(); COMPUTE(2);
  WAITV(0);  BAR(); COMPUTE(3);

  // ===== fused epilogue: T1 tile = relu(acc) @ W1 =====
  // 1) relu + transpose acc (C layout) -> tbuf A-readable [16][128] bf16,
  //    swizzle (row&15)<<4. tbuf = wave's own slice of A-buf0 (private).
  char* tbuf = sMem + w * 4096;
#pragma unroll
  for (int dt = 0; dt < 8; ++dt) {
#pragma unroll
    for (int r = 0; r < 4; ++r) {
      float v = acc[dt][r];
      v = v > 0.f ? v : 0.f;
      const int row = kgrp * 4 + r;
      const int byte = (row * 256 + (dt * 16 + arow) * 2) ^ ((row & 15) << 4);
      *(short*)(tbuf + byte) = f2bf(v);
    }
  }
  __syncthreads();   // all waves done with pipeline LDS; safe to repurpose sB

  // 2) stage W1 -> LDS as bf16 B-frags (all 256 threads): W1fL at sMem+98304
  {
    short* W1fL = (short*)(sMem + 98304);
    const float4* W14 = (const float4*)W1;
    for (int it = 0; it < 16; ++it) {
      const int lin = tid + it * 256;          // 0..4095
      const int j  = lin >> 5;                 // k-row 0..127
      const int d4 = lin & 31;                 // float4 col
      float4 wv = W14[j * 32 + d4];
      float wa[4] = {wv.x, wv.y, wv.z, wv.w};
      const int ks = j >> 5, ksub = (j >> 3) & 3, e = j & 7;
#pragma unroll
      for (int c = 0; c < 4; ++c) {
        const int d = d4 * 4 + c;
        const int dt = d >> 4;
        const int lf = (d & 15) | (ksub << 4);
        W1fL[((ks * 8 + dt) * 64 + lf) * 8 + e] = f2bf(wa[c]);
      }
    }
  }
  __syncthreads();

  // 3) 32 MFMAs: nacc = tbuf(A-frags) x W1fL(B-frags)
  f32x4 nacc[8];
#pragma unroll
  for (int dt = 0; dt < 8; ++dt) nacc[dt] = (f32x4){0.f, 0.f, 0.f, 0.f};
  {
    const short* W1fL = (const short*)(sMem + 98304);
#pragma unroll
    for (int ks = 0; ks < 4; ++ks) {
      short8 af = *(const short8*)(tbuf +
          ((arow * 256 + (ks * 32 + kgrp * 8) * 2) ^ ((arow & 15) << 4)));
#pragma unroll
      for (int dt = 0; dt < 8; ++dt) {
        short8 wf = *(const short8*)&W1fL[((ks * 8 + dt) * 64 + lane) * 8];
        nacc[dt] = __builtin_amdgcn_mfma_f32_16x16x32_bf16(af, wf, nacc[dt], 0, 0, 0);
      }
    }
  }

  // 4) pair-wise assembly into B-frag-linear obuf, then contiguous stores
  char* obuf = sMem + 65536 + (w >> 1) * 8192;   // 8 KB per wave-pair
  const int wp = w & 1;
#pragma unroll
  for (int dt = 0; dt < 8; ++dt) {
#pragma unroll
    for (int r = 0; r < 4; ++r) {
      const int kl = wp * 16 + kgrp * 4 + r;     // 0..31 within pair k-tile
      const int lf = arow | ((kl >> 3) << 4);
      const int e  = kl & 7;
      *(short*)(obuf + (dt * 512 + lf * 8 + e) * 2) = f2bf(nacc[dt][r]);
    }
  }
  __syncthreads();
  const long kt = (long)blockIdx.x * 2 + (w >> 1);
#pragma unroll
  for (int i = 0; i < 4; ++i) {
    const int dt = wp * 4 + i;
    short8 vv = *(const short8*)(obuf + (dt * 512 + lane * 8) * 2);
    *(short8*)(T1f + ((kt * 8 + dt) * 64 + lane) * 8) = vv;
  }
}

// ---------------------------------------------------------------------------
// agg layer 2 (R9 structure exactly): out = relu(A @ T1), fp32 out.
// ---------------------------------------------------------------------------
__global__ __launch_bounds__(256, 1)
void agg_kernel(const float* __restrict__ A, const short* __restrict__ Bf,
                float* __restrict__ out_)
{
  __shared__ __align__(16) char sMem[131072];    // A: 4x16KB | B: 4x16KB
  char* sA = sMem;
  char* sB = sMem + 65536;

  const int tid  = threadIdx.x;
  const int lane = tid & 63;
  const int w    = tid >> 6;
  const long rb  = (long)blockIdx.x * 64;
  const int arow = lane & 15;
  const int kgrp = lane >> 4;

  int rowi[4], colfi[4];
#pragma unroll
  for (int i = 0; i < 4; ++i) {
    const int o  = w * 4096 + i * 1024 + lane * 16;
    const int rr = o >> 8;
    const int cb = (o & 255) ^ ((rr & 7) << 4);
    rowi[i] = rr;
    colfi[i] = cb >> 2;
  }
  const short* gsrcB = Bf + w * 2048 + lane * 8;
  char* ldsAu = sA + w * 4096;
  char* ldsBu = sB + w * 4096;

  f32x4 acc[8];
#pragma unroll
  for (int dt = 0; dt < 8; ++dt) acc[dt] = (f32x4){0.f, 0.f, 0.f, 0.f};

  auto STAGE = [&](int buf, int t) {
#pragma unroll
    for (int i = 0; i < 4; ++i) {
      const float* g = A + (rb + rowi[i]) * (long)NN + t * BK + colfi[i];
      __builtin_amdgcn_global_load_lds(
          (const __attribute__((address_space(1))) unsigned int*)g,
          (__attribute__((address_space(3))) unsigned int*)(ldsAu + buf * 16384 + i * 1024),
          16, 0, 0x12);
    }
    const short* g = gsrcB + (long)t * 8192;
#pragma unroll
    for (int i = 0; i < 4; ++i)
      __builtin_amdgcn_global_load_lds(
          (const __attribute__((address_space(1))) unsigned int*)(g + i * 512),
          (__attribute__((address_space(3))) unsigned int*)(ldsBu + buf * 16384 + i * 1024),
          16, 0, 0);
  };

  auto COMPUTE = [&](int buf) {
    const char* la = sA + buf * 16384;
    const char* lb = sB + buf * 16384 + lane * 16;
    const int row = w * 16 + arow;
    const int sw  = (arow & 7) << 4;
#pragma unroll
    for (int ks = 0; ks < 2; ++ks) {
      f32x4 a0 = *(const f32x4*)(la + row * 256 + ((ks * 128 + kgrp * 32) ^ sw));
      f32x4 a1 = *(const f32x4*)(la + row * 256 + ((ks * 128 + kgrp * 32 + 16) ^ sw));
      short8 af;
      af[0] = f2bf(a0.x); af[1] = f2bf(a0.y); af[2] = f2bf(a0.z); af[3] = f2bf(a0.w);
      af[4] = f2bf(a1.x); af[5] = f2bf(a1.y); af[6] = f2bf(a1.z); af[7] = f2bf(a1.w);
#pragma unroll
      for (int dt = 0; dt < 8; ++dt) {
        short8 bf = *(const short8*)(lb + (ks * 8 + dt) * 1024);
        acc[dt] = __builtin_amdgcn_mfma_f32_16x16x32_bf16(af, bf, acc[dt], 0, 0, 0);
      }
    }
  };

  STAGE(0, 0); STAGE(1, 1); STAGE(2, 2);

  int t = 0;
  for (; t < NT - 4; t += 4) {
    WAITV(16); BAR(); STAGE(3, t + 3); COMPUTE(0);
    WAITV(16); BAR(); STAGE(0, t + 4); COMPUTE(1);
    WAITV(16); BAR(); STAGE(1, t + 5); COMPUTE(2);
    WAITV(16); BAR(); STAGE(2, t + 6); COMPUTE(3);
  }
  WAITV(16); BAR(); STAGE(3, t + 3); COMPUTE(0);
  WAITV(16); BAR(); COMPUTE(1);
  WAITV(8);  BAR(); COMPUTE(2);
  WAITV(0);  BAR(); COMPUTE(3);

#pragma unroll
  for (int dt = 0; dt < 8; ++dt) {
#pragma unroll
    for (int r = 0; r < 4; ++r) {
      float v = acc[dt][r];
      v = v > 0.f ? v : 0.f;
      const long row = rb + w * 16 + kgrp * 4 + r;
      const int  col = dt * 16 + arow;
      __builtin_nontemporal_store(v, out_ + row * DD + col);
    }
  }
}

// ---------------------------------------------------------------------------
extern "C" void kernel_launch(void* const* d_in, const int* in_sizes, int n_in,
                              void* d_out, int out_size, void* d_ws, size_t ws_size,
                              hipStream_t stream)
{
  const float* A  = (const float*)d_in[0];   // [16384][16384]
  const float* X  = (const float*)d_in[1];   // [16384][128]
  const float* W0 = (const float*)d_in[2];   // [128][128]
  const float* W1 = (const float*)d_in[3];   // [128][128]

  short* T0f = (short*)d_ws;                 // bf16 fragment-major T0 (4 MB)
  short* T1f = T0f + (size_t)DD * NN;        // bf16 fragment-major T1 (4 MB)

  // T0 = X @ W0 (frag-major)
  small_gemm<0><<<NN / 16, 256, 0, stream>>>(X, W0, T0f);
  // fused: T1f = frag(relu(A @ T0) @ W1)   (no H1 round-trip)
  agg_fused<<<NN / 64, 256, 0, stream>>>(A, T0f, W1, T1f);
  // out = relu(A @ T1)
  agg_kernel<<<NN / 64, 256, 0, stream>>>(A, T1f, (float*)d_out);
}

// Round 15
// 398.735 us; speedup vs baseline: 1.9846x; 1.0961x over previous
//
#include <hip/hip_runtime.h>
#include <hip/hip_bf16.h>

#define NN 16384
#define DD 128
#define BK 64          // k floats per pipeline stage
#define NT (NN / BK)   // 256 stages

typedef __attribute__((ext_vector_type(8))) short short8;
typedef __attribute__((ext_vector_type(4))) float f32x4;

__device__ __forceinline__ short f2bf(float f) {
  union { float f; unsigned u; } v; v.f = f;
  unsigned r = v.u + 0x7fffu + ((v.u >> 16) & 1u);   // RNE f32->bf16
  return (short)(r >> 16);
}
__device__ __forceinline__ float bf2f(short s) {
  union { unsigned u; float f; } v; v.u = ((unsigned)(unsigned short)s) << 16;
  return v.f;
}

#define WAITV(n) asm volatile("s_waitcnt vmcnt(" #n ")" ::: "memory")
#define BAR()    do { __builtin_amdgcn_s_barrier(); asm volatile("" ::: "memory"); } while (0)

// ---------------------------------------------------------------------------
// small GEMM: T = X @ W0, written in MFMA B-fragment-major layout:
//   element (d, k):  kt=k>>5, dt=d>>4, lane=(d&15)|(((k>>3)&3)<<4), e=k&7
//   Tf[(((kt*8)+dt)*64 + lane)*8 + e]
// ---------------------------------------------------------------------------
__global__ __launch_bounds__(256, 1)
void small_gemm(const float* __restrict__ In_, const float* __restrict__ W,
                short* __restrict__ Tf)
{
  __shared__ float sW[DD * DD];   // 64 KB
  const int tid = threadIdx.x;
  {
    const float4* W4 = (const float4*)W;
    float4* sW4 = (float4*)sW;
#pragma unroll
    for (int i = 0; i < 16; ++i) sW4[tid + 256 * i] = W4[tid + 256 * i];
  }
  __syncthreads();

  const int k0 = blockIdx.x * 16;
  const int kk = tid & 15;        // k-row within tile
  const int q  = tid >> 4;        // d-chunk 0..15 -> d = 8q..8q+7
  const long rowoff = (long)(k0 + kk) * DD;

  float acc[8] = {0.f, 0.f, 0.f, 0.f, 0.f, 0.f, 0.f, 0.f};
  const float4* In4 = (const float4*)(In_ + rowoff);
  for (int j4 = 0; j4 < 32; ++j4) {
    float4 a4 = In4[j4];
    float av[4] = {a4.x, a4.y, a4.z, a4.w};
#pragma unroll
    for (int c = 0; c < 4; ++c)
#pragma unroll
      for (int dd = 0; dd < 8; ++dd)
        acc[dd] += av[c] * sW[(j4 * 4 + c) * DD + q * 8 + dd];
  }

  const int k    = k0 + kk;
  const int kt   = k >> 5;
  const int ksub = (k >> 3) & 3;
  const int e    = k & 7;
#pragma unroll
  for (int dd = 0; dd < 8; ++dd) {
    const int d  = q * 8 + dd;
    const int dt = d >> 4;
    const int lf = (d & 15) | (ksub << 4);
    Tf[((((long)kt * 8) + dt) * 64 + lf) * 8 + e] = f2bf(acc[dd]);
  }
}

// ===========================================================================
// 8-WAVE agg (512 thr, 2 waves/SIMD): BM=64 rows, wave (rw=w&3, dh=w>>2)
// owns rows rw*16..+15 x cols dh*64..+63. Per-CU staging/HBM identical to
// R14; per-wave work halved so the second wave per SIMD hides the
// WAITV+barrier stall of the first. 4 VMEM/phase/wave -> WAITV(8) steady.
// ===========================================================================

// common main-loop macro body via lambdas (written out in each kernel)

// ---------------------------------------------------------------------------
// FUSED agg layer 1: T1f = frag((relu(A @ T0)) @ W1)
// ---------------------------------------------------------------------------
__global__ __launch_bounds__(512, 1)
void agg_fused(const float* __restrict__ A, const short* __restrict__ Bf,
               const float* __restrict__ W1, short* __restrict__ T1f)
{
  __shared__ __align__(16) char sMem[131072];    // A: 4x16KB | B: 4x16KB
  char* sA = sMem;
  char* sB = sMem + 65536;

  const int tid  = threadIdx.x;
  const int lane = tid & 63;
  const int w    = tid >> 6;                     // wave 0..7
  const int rw   = w & 3;                        // row group
  const int dh   = w >> 2;                       // dt half
  const long rb  = (long)blockIdx.x * 64;
  const int arow = lane & 15;
  const int kgrp = lane >> 4;

  int rowi[2], colfi[2];
#pragma unroll
  for (int i = 0; i < 2; ++i) {
    const int o  = (2 * w + i) * 1024 + lane * 16;
    const int rr = o >> 8;
    const int cb = (o & 255) ^ ((rr & 7) << 4);
    rowi[i] = rr;
    colfi[i] = cb >> 2;
  }

  f32x4 acc[4];
#pragma unroll
  for (int j = 0; j < 4; ++j) acc[j] = (f32x4){0.f, 0.f, 0.f, 0.f};

  auto STAGE = [&](int buf, int t) {
#pragma unroll
    for (int i = 0; i < 2; ++i) {
      const float* g = A + (rb + rowi[i]) * (long)NN + t * BK + colfi[i];
      __builtin_amdgcn_global_load_lds(
          (const __attribute__((address_space(1))) unsigned int*)g,
          (__attribute__((address_space(3))) unsigned int*)(sA + buf * 16384 + (2 * w + i) * 1024),
          16, 0, 0x12);
    }
#pragma unroll
    for (int i = 0; i < 2; ++i) {
      const short* g = Bf + (long)t * 8192 + (2 * w + i) * 512 + lane * 8;
      __builtin_amdgcn_global_load_lds(
          (const __attribute__((address_space(1))) unsigned int*)g,
          (__attribute__((address_space(3))) unsigned int*)(sB + buf * 16384 + (2 * w + i) * 1024),
          16, 0, 0);
    }
  };

  auto COMPUTE = [&](int buf) {
    const char* la = sA + buf * 16384;
    const char* lb = sB + buf * 16384 + lane * 16;
    const int row = rw * 16 + arow;
    const int sw  = (arow & 7) << 4;
#pragma unroll
    for (int ks = 0; ks < 2; ++ks) {
      f32x4 a0 = *(const f32x4*)(la + row * 256 + ((ks * 128 + kgrp * 32) ^ sw));
      f32x4 a1 = *(const f32x4*)(la + row * 256 + ((ks * 128 + kgrp * 32 + 16) ^ sw));
      short8 af;
      af[0] = f2bf(a0.x); af[1] = f2bf(a0.y); af[2] = f2bf(a0.z); af[3] = f2bf(a0.w);
      af[4] = f2bf(a1.x); af[5] = f2bf(a1.y); af[6] = f2bf(a1.z); af[7] = f2bf(a1.w);
#pragma unroll
      for (int j = 0; j < 4; ++j) {
        short8 bf = *(const short8*)(lb + (ks * 8 + dh * 4 + j) * 1024);
        acc[j] = __builtin_amdgcn_mfma_f32_16x16x32_bf16(af, bf, acc[j], 0, 0, 0);
      }
    }
  };

  STAGE(0, 0); STAGE(1, 1); STAGE(2, 2);

  int t = 0;
  for (; t < NT - 4; t += 4) {
    WAITV(8); BAR(); STAGE(3, t + 3); COMPUTE(0);
    WAITV(8); BAR(); STAGE(0, t + 4); COMPUTE(1);
    WAITV(8); BAR(); STAGE(1, t + 5); COMPUTE(2);
    WAITV(8); BAR(); STAGE(2, t + 6); COMPUTE(3);
  }
  WAITV(8); BAR(); STAGE(3, t + 3); COMPUTE(0);
  WAITV(8); BAR(); COMPUTE(1);
  WAITV(4); BAR(); COMPUTE(2);
  WAITV(0); BAR(); COMPUTE(3);

  // ===== fused epilogue: T1 tile = relu(acc) @ W1 =====
  // 1) relu + transpose -> tbuf[rw] ([16][128] bf16, swizzle (row&15)<<4);
  //    dh-pair writes disjoint column halves.
  char* tbuf = sMem + rw * 4096;
#pragma unroll
  for (int j = 0; j < 4; ++j) {
#pragma unroll
    for (int r = 0; r < 4; ++r) {
      float v = acc[j][r];
      v = v > 0.f ? v : 0.f;
      const int rowl = kgrp * 4 + r;
      const int col  = (dh * 4 + j) * 16 + arow;
      const int byte = (rowl * 256 + col * 2) ^ ((rowl & 15) << 4);
      *(short*)(tbuf + byte) = f2bf(v);
    }
  }
  __syncthreads();

  // 2) stage W1 -> LDS bf16 B-frags (512 threads, 8 iters)
  {
    short* W1fL = (short*)(sMem + 98304);
    const float4* W14 = (const float4*)W1;
    for (int it = 0; it < 8; ++it) {
      const int lin = tid + it * 512;          // 0..4095
      const int j  = lin >> 5;                 // k-row 0..127
      const int d4 = lin & 31;
      float4 wv = W14[j * 32 + d4];
      float wa[4] = {wv.x, wv.y, wv.z, wv.w};
      const int ks = j >> 5, ksub = (j >> 3) & 3, e = j & 7;
#pragma unroll
      for (int c = 0; c < 4; ++c) {
        const int d = d4 * 4 + c;
        const int dt = d >> 4;
        const int lf = (d & 15) | (ksub << 4);
        W1fL[((ks * 8 + dt) * 64 + lf) * 8 + e] = f2bf(wa[c]);
      }
    }
  }
  __syncthreads();

  // 3) 16 MFMAs/wave: nacc = tbuf(A-frags of rw) x W1fL(dt-half dh)
  f32x4 nacc[4];
#pragma unroll
  for (int j = 0; j < 4; ++j) nacc[j] = (f32x4){0.f, 0.f, 0.f, 0.f};
  {
    const short* W1fL = (const short*)(sMem + 98304);
#pragma unroll
    for (int ks = 0; ks < 4; ++ks) {
      short8 af = *(const short8*)(tbuf +
          ((arow * 256 + (ks * 32 + kgrp * 8) * 2) ^ ((arow & 15) << 4)));
#pragma unroll
      for (int j = 0; j < 4; ++j) {
        short8 wf = *(const short8*)&W1fL[((ks * 8 + dh * 4 + j) * 64 + lane) * 8];
        nacc[j] = __builtin_amdgcn_mfma_f32_16x16x32_bf16(af, wf, nacc[j], 0, 0, 0);
      }
    }
  }

  // 4) assembly into B-frag-linear obuf (8 KB per kt), contiguous stores
  char* obuf = sMem + 65536 + (rw >> 1) * 8192;
  const int kh = rw & 1;
#pragma unroll
  for (int j = 0; j < 4; ++j) {
#pragma unroll
    for (int r = 0; r < 4; ++r) {
      const int dt = dh * 4 + j;
      const int kl = kh * 16 + kgrp * 4 + r;   // 0..31 within k-tile
      const int lf = arow | ((kl >> 3) << 4);
      const int e  = kl & 7;
      *(short*)(obuf + (dt * 512 + lf * 8 + e) * 2) = f2bf(nacc[j][r]);
    }
  }
  __syncthreads();
  {
    const long ktg = (long)blockIdx.x * 2 + (w >> 2);
    const char* obr = sMem + 65536 + ((w >> 2) & 1) * 8192;
#pragma unroll
    for (int i = 0; i < 2; ++i) {
      const int dt = (w & 3) * 2 + i;
      short8 vv = *(const short8*)(obr + (dt * 512 + lane * 8) * 2);
      *(short8*)(T1f + ((ktg * 8 + dt) * 64 + lane) * 8) = vv;
    }
  }
}

// ---------------------------------------------------------------------------
// agg layer 2 (8-wave): out = relu(A @ T1), fp32 out.
// ---------------------------------------------------------------------------
__global__ __launch_bounds__(512, 1)
void agg_kernel(const float* __restrict__ A, const short* __restrict__ Bf,
                float* __restrict__ out_)
{
  __shared__ __align__(16) char sMem[131072];
  char* sA = sMem;
  char* sB = sMem + 65536;

  const int tid  = threadIdx.x;
  const int lane = tid & 63;
  const int w    = tid >> 6;
  const int rw   = w & 3;
  const int dh   = w >> 2;
  const long rb  = (long)blockIdx.x * 64;
  const int arow = lane & 15;
  const int kgrp = lane >> 4;

  int rowi[2], colfi[2];
#pragma unroll
  for (int i = 0; i < 2; ++i) {
    const int o  = (2 * w + i) * 1024 + lane * 16;
    const int rr = o >> 8;
    const int cb = (o & 255) ^ ((rr & 7) << 4);
    rowi[i] = rr;
    colfi[i] = cb >> 2;
  }

  f32x4 acc[4];
#pragma unroll
  for (int j = 0; j < 4; ++j) acc[j] = (f32x4){0.f, 0.f, 0.f, 0.f};

  auto STAGE = [&](int buf, int t) {
#pragma unroll
    for (int i = 0; i < 2; ++i) {
      const float* g = A + (rb + rowi[i]) * (long)NN + t * BK + colfi[i];
      __builtin_amdgcn_global_load_lds(
          (const __attribute__((address_space(1))) unsigned int*)g,
          (__attribute__((address_space(3))) unsigned int*)(sA + buf * 16384 + (2 * w + i) * 1024),
          16, 0, 0x12);
    }
#pragma unroll
    for (int i = 0; i < 2; ++i) {
      const short* g = Bf + (long)t * 8192 + (2 * w + i) * 512 + lane * 8;
      __builtin_amdgcn_global_load_lds(
          (const __attribute__((address_space(1))) unsigned int*)g,
          (__attribute__((address_space(3))) unsigned int*)(sB + buf * 16384 + (2 * w + i) * 1024),
          16, 0, 0);
    }
  };

  auto COMPUTE = [&](int buf) {
    const char* la = sA + buf * 16384;
    const char* lb = sB + buf * 16384 + lane * 16;
    const int row = rw * 16 + arow;
    const int sw  = (arow & 7) << 4;
#pragma unroll
    for (int ks = 0; ks < 2; ++ks) {
      f32x4 a0 = *(const f32x4*)(la + row * 256 + ((ks * 128 + kgrp * 32) ^ sw));
      f32x4 a1 = *(const f32x4*)(la + row * 256 + ((ks * 128 + kgrp * 32 + 16) ^ sw));
      short8 af;
      af[0] = f2bf(a0.x); af[1] = f2bf(a0.y); af[2] = f2bf(a0.z); af[3] = f2bf(a0.w);
      af[4] = f2bf(a1.x); af[5] = f2bf(a1.y); af[6] = f2bf(a1.z); af[7] = f2bf(a1.w);
#pragma unroll
      for (int j = 0; j < 4; ++j) {
        short8 bf = *(const short8*)(lb + (ks * 8 + dh * 4 + j) * 1024);
        acc[j] = __builtin_amdgcn_mfma_f32_16x16x32_bf16(af, bf, acc[j], 0, 0, 0);
      }
    }
  };

  STAGE(0, 0); STAGE(1, 1); STAGE(2, 2);

  int t = 0;
  for (; t < NT - 4; t += 4) {
    WAITV(8); BAR(); STAGE(3, t + 3); COMPUTE(0);
    WAITV(8); BAR(); STAGE(0, t + 4); COMPUTE(1);
    WAITV(8); BAR(); STAGE(1, t + 5); COMPUTE(2);
    WAITV(8); BAR(); STAGE(2, t + 6); COMPUTE(3);
  }
  WAITV(8); BAR(); STAGE(3, t + 3); COMPUTE(0);
  WAITV(8); BAR(); COMPUTE(1);
  WAITV(4); BAR(); COMPUTE(2);
  WAITV(0); BAR(); COMPUTE(3);

#pragma unroll
  for (int j = 0; j < 4; ++j) {
#pragma unroll
    for (int r = 0; r < 4; ++r) {
      float v = acc[j][r];
      v = v > 0.f ? v : 0.f;
      const long row = rb + rw * 16 + kgrp * 4 + r;
      const int  col = (dh * 4 + j) * 16 + arow;
      __builtin_nontemporal_store(v, out_ + row * DD + col);
    }
  }
}

// ---------------------------------------------------------------------------
extern "C" void kernel_launch(void* const* d_in, const int* in_sizes, int n_in,
                              void* d_out, int out_size, void* d_ws, size_t ws_size,
                              hipStream_t stream)
{
  const float* A  = (const float*)d_in[0];   // [16384][16384]
  const float* X  = (const float*)d_in[1];   // [16384][128]
  const float* W0 = (const float*)d_in[2];   // [128][128]
  const float* W1 = (const float*)d_in[3];   // [128][128]

  short* T0f = (short*)d_ws;                 // bf16 fragment-major T0 (4 MB)
  short* T1f = T0f + (size_t)DD * NN;        // bf16 fragment-major T1 (4 MB)

  small_gemm<<<NN / 16, 256, 0, stream>>>(X, W0, T0f);
  agg_fused<<<NN / 64, 512, 0, stream>>>(A, T0f, W1, T1f);
  agg_kernel<<<NN / 64, 512, 0, stream>>>(A, T1f, (float*)d_out);
}